// Round 3
// baseline (559.576 us; speedup 1.0000x reference)
//
#include <hip/hip_runtime.h>

#define NEGV (-10000.0f)

namespace {
constexpr int Bn = 256;   // batch
constexpr int Sn = 1024;  // sequence length
constexpr int Tn = 128;   // tags incl. start/end
constexpr int START_TAG = 126;
constexpr int END_TAG = 127;

__device__ __forceinline__ float wave_max(float v) {
#pragma unroll
  for (int off = 32; off >= 1; off >>= 1) v = fmaxf(v, __shfl_xor(v, off));
  return v;
}
__device__ __forceinline__ float wave_sum(float v) {
#pragma unroll
  for (int off = 32; off >= 1; off >>= 1) v += __shfl_xor(v, off);
  return v;
}

// ws layout (floats):
//   [0, Bn*Tn)            : a_511 per batch (normalized)
//   [Bn*Tn, 2*Bn*Tn)      : b_511 per batch (normalized)
//   [2*Bn*Tn, +Bn*4)      : per-batch scalars {logoff_a, gold_a, logoff_b, gold_b}

__global__ __launch_bounds__(256, 2) void crf_chain(
    const float* __restrict__ em, const int* __restrict__ tags,
    const float* __restrict__ trans, float* __restrict__ ws) {
  const int bid = blockIdx.x;
  const bool isf = (bid < Bn);          // forward or backward chain
  const int b = isf ? bid : (bid - Bn);
  const int tid = threadIdx.x;          // 256 threads
  const int j = tid & (Tn - 1);         // output index (column for fwd, row for bwd)
  const int h = tid >> 7;               // which half of the reduction axis

  __shared__ float sv[Tn];       // current state vector (alpha for fwd, g for bwd)
  __shared__ float part[2][Tn];  // per-half partial sums
  __shared__ float red[8];

  const float* embase = em + (size_t)b * Sn * Tn;

  // E slice in registers: fwd thread owns column j of exp(trans) (i in [64h,64h+64));
  // bwd thread owns row j of exp(trans) (jj in [64h,64h+64)).
  float E[64];
  if (isf) {
#pragma unroll
    for (int k = 0; k < 64; ++k) E[k] = __expf(trans[(64 * h + k) * Tn + j]);
  } else {
#pragma unroll
    for (int k = 0; k < 64; ++k) E[k] = __expf(trans[j * Tn + 64 * h + k]);
  }

  float logoff = isf ? 0.f : NEGV;
  if (tid < Tn) {
    if (isf) {
      sv[tid] = (tid == START_TAG) ? 1.f : 0.f;  // a_0 = onehot(start)
    } else {
      // g_init = exp(trans[end][j] - NEGV + em[S-1][j]); logoff_b = NEGV
      sv[tid] = __expf(trans[END_TAG * Tn + tid] - NEGV +
                       embase[(size_t)(Sn - 1) * Tn + tid]);
    }
  }
  __syncthreads();

  // fwd: 511 matvecs -> a_511 ; bwd: 512 matvecs -> b_511 (meet at t=511)
  const int iters = isf ? (Sn / 2 - 1) : (Sn / 2);
  float em_cur = 0.f;
  if (h == 0) em_cur = embase[(size_t)(isf ? 1 : (Sn - 2)) * Tn + j];

  for (int n = 1; n <= iters; ++n) {
    const bool mul = isf || (n < iters);  // bwd's last matvec has no emission factor
    const bool has_next = isf ? (n < iters) : (n + 1 < iters);
    float ex = 1.f, em_next = 0.f;
    if (h == 0) {
      if (mul) ex = __expf(em_cur);
      if (has_next) {
        const int idx = isf ? (n + 1) : (Sn - 2 - n);
        em_next = embase[(size_t)idx * Tn + j];  // prefetch next emission row
      }
    }

    // matvec over this thread's half of the reduction axis (8 accs break dep chain)
    float a0 = 0.f, a1 = 0.f, a2 = 0.f, a3 = 0.f, a4 = 0.f, a5 = 0.f, a6 = 0.f, a7 = 0.f;
    const int base = 64 * h;
#pragma unroll
    for (int k = 0; k < 64; k += 8) {
      a0 = fmaf(sv[base + k + 0], E[k + 0], a0);
      a1 = fmaf(sv[base + k + 1], E[k + 1], a1);
      a2 = fmaf(sv[base + k + 2], E[k + 2], a2);
      a3 = fmaf(sv[base + k + 3], E[k + 3], a3);
      a4 = fmaf(sv[base + k + 4], E[k + 4], a4);
      a5 = fmaf(sv[base + k + 5], E[k + 5], a5);
      a6 = fmaf(sv[base + k + 6], E[k + 6], a6);
      a7 = fmaf(sv[base + k + 7], E[k + 7], a7);
    }
    part[h][j] = ((a0 + a1) + (a2 + a3)) + ((a4 + a5) + (a6 + a7));
    __syncthreads();

    const bool ren = ((n & 3) == 3);
    if (h == 0) {
      const float v = (part[0][j] + part[1][j]) * ex;
      sv[j] = v;
      if (ren) {
        const float m = wave_max(v);
        if ((tid & 63) == 0) red[tid >> 6] = m;
      }
      em_cur = em_next;
    }
    __syncthreads();
    if (ren) {
      if (h == 0) {
        const float m = fmaxf(red[0], red[1]);
        sv[j] *= __builtin_amdgcn_rcpf(m);
        logoff += __logf(m);
      }
      __syncthreads();
    }
  }

  // final renormalize + store vector and log-offset
  if (h == 0) {
    const float m = wave_max(sv[j]);
    if ((tid & 63) == 0) red[tid >> 6] = m;
  }
  __syncthreads();
  float* vec_out = ws + (isf ? 0 : Bn * Tn) + b * Tn;
  float* scal = ws + 2 * Bn * Tn + b * 4;
  if (h == 0) {
    const float m = fmaxf(red[0], red[1]);
    vec_out[j] = sv[j] * __builtin_amdgcn_rcpf(m);
    if (tid == 0) scal[isf ? 0 : 2] = logoff + __logf(m);
  }
  __syncthreads();

  // ---- gold path score (each chain covers its half of t) ----
  const int* tg = tags + b * Sn;
  float g = 0.f;
  const int t0 = isf ? 0 : (Sn / 2);
  for (int t = t0 + tid; t < t0 + Sn / 2; t += 256) {
    const int tag = tg[t];
    g += embase[(size_t)t * Tn + tag];
    if (isf) {
      if (t < Sn / 2 - 1) g += trans[tag * Tn + tg[t + 1]];
    } else {
      g += trans[tg[t - 1] * Tn + tag];  // covers pairs (511,512)..(1022,1023)
    }
  }
  if (tid == 0)
    g += isf ? trans[START_TAG * Tn + tg[0]] : trans[tg[Sn - 1] * Tn + END_TAG];
  g = wave_sum(g);
  if ((tid & 63) == 0) red[4 + (tid >> 6)] = g;
  __syncthreads();
  if (tid == 0) scal[isf ? 1 : 3] = red[4] + red[5] + red[6] + red[7];
}

__global__ void crf_final(const float* __restrict__ ws, float* __restrict__ out) {
  const int tid = threadIdx.x;  // 256 threads = one per batch
  const float* av = ws + tid * Tn;
  const float* bv = ws + Bn * Tn + tid * Tn;
  const float* scal = ws + 2 * Bn * Tn + tid * 4;
  float dot = 0.f;
#pragma unroll 4
  for (int k = 0; k < Tn / 4; ++k) {
    const float4 a4 = reinterpret_cast<const float4*>(av)[k];
    const float4 b4 = reinterpret_cast<const float4*>(bv)[k];
    dot += a4.x * b4.x + a4.y * b4.y + a4.z * b4.z + a4.w * b4.w;
  }
  const float partition = scal[0] + scal[2] + __logf(dot);
  const float loss = partition - scal[1] - scal[3];
  float s = wave_sum(loss);
  __shared__ float r[4];
  if ((tid & 63) == 0) r[tid >> 6] = s;
  __syncthreads();
  if (tid == 0) out[0] = (r[0] + r[1] + r[2] + r[3]) * (1.f / Bn);
}

}  // namespace

extern "C" void kernel_launch(void* const* d_in, const int* in_sizes, int n_in,
                              void* d_out, int out_size, void* d_ws, size_t ws_size,
                              hipStream_t stream) {
  (void)in_sizes; (void)n_in; (void)out_size; (void)ws_size;
  const float* em = (const float*)d_in[0];
  const int* tags = (const int*)d_in[1];
  const float* trans = (const float*)d_in[2];
  float* out = (float*)d_out;
  float* ws = (float*)d_ws;

  crf_chain<<<dim3(2 * Bn), dim3(256), 0, stream>>>(em, tags, trans, ws);
  crf_final<<<dim3(1), dim3(256), 0, stream>>>(ws, out);
}

// Round 4
// 435.792 us; speedup vs baseline: 1.2840x; 1.2840x over previous
//
#include <hip/hip_runtime.h>

#define NEGV (-10000.0f)

namespace {
constexpr int Bn = 256;   // batch
constexpr int Sn = 1024;  // sequence length
constexpr int Tn = 128;   // tags incl. start/end
constexpr int START_TAG = 126;
constexpr int END_TAG = 127;

typedef float f32x4 __attribute__((ext_vector_type(4)));

template <int CTRL>
__device__ __forceinline__ float dppf(float x) {
  return __int_as_float(
      __builtin_amdgcn_update_dpp(0, __float_as_int(x), CTRL, 0xF, 0xF, false));
}
__device__ __forceinline__ float rl63(float x) {
  return __int_as_float(__builtin_amdgcn_readlane(__float_as_int(x), 63));
}
__device__ __forceinline__ float wave_sum(float v) {
#pragma unroll
  for (int off = 32; off >= 1; off >>= 1) v += __shfl_xor(v, off);
  return v;
}

// ws layout (floats):
//   [0, Bn*Tn)         : a_511 per batch (normalized)
//   [Bn*Tn, 2*Bn*Tn)   : b_511 per batch (normalized)
//   [2*Bn*Tn, +Bn*4)   : per-batch scalars {logoff_a, gold_a, logoff_b, gold_b}

// Layout: 256 threads = 4 waves. lane l: s = l&7 (depth slice, i in [16s,16s+16)),
// g = (l>>3) + 8*wave (j-group, owns j = 4g..4g+3). E fragment = 16 named f32x4
// (64 VGPRs, statically indexed -> register-resident). sv in LDS, sectioned
// layout word(i) = 20*(i>>4) + (i&15): the 8 per-slice b128 read addresses hit 8
// disjoint bank-quads (20s mod 32 all distinct quads) -> conflict-free broadcast.
// Partial reduce over 8 slices via DPP butterfly (VALU pipe, no LDS).

#define DECLE(i) f32x4 E##i;
#define INITE(i)                                                              \
  if (isf) {                                                                  \
    f32x4 tv = *(const f32x4*)(trans + (16 * s + i) * Tn + 4 * g);            \
    E##i = (f32x4){__expf(tv.x), __expf(tv.y), __expf(tv.z), __expf(tv.w)};   \
  } else {                                                                    \
    E##i = (f32x4){__expf(trans[(4 * g + 0) * Tn + 16 * s + i]),              \
                   __expf(trans[(4 * g + 1) * Tn + 16 * s + i]),              \
                   __expf(trans[(4 * g + 2) * Tn + 16 * s + i]),              \
                   __expf(trans[(4 * g + 3) * Tn + 16 * s + i])};             \
  }

__global__ __launch_bounds__(256, 2) void crf_chain(
    const float* __restrict__ em, const int* __restrict__ tags,
    const float* __restrict__ trans, float* __restrict__ ws) {
  const int bid = blockIdx.x;
  const bool isf = (bid < Bn);
  const int b = isf ? bid : (bid - Bn);
  const int tid = threadIdx.x;
  const int w = tid >> 6;
  const int l = tid & 63;
  const int s = l & 7;
  const int g = (l >> 3) + 8 * w;

  __shared__ __align__(16) float sv[2][160];  // double-buffered state, sectioned
  __shared__ __align__(16) float red[4];      // per-wave renorm max exchange
  __shared__ float gred[4];                   // gold-score reduction

  const float* embase = em + (size_t)b * Sn * Tn;

  DECLE(0) DECLE(1) DECLE(2) DECLE(3) DECLE(4) DECLE(5) DECLE(6) DECLE(7)
  DECLE(8) DECLE(9) DECLE(10) DECLE(11) DECLE(12) DECLE(13) DECLE(14) DECLE(15)
  INITE(0) INITE(1) INITE(2) INITE(3) INITE(4) INITE(5) INITE(6) INITE(7)
  INITE(8) INITE(9) INITE(10) INITE(11) INITE(12) INITE(13) INITE(14) INITE(15)

  if (tid < Tn) {
    float v;
    if (isf) {
      v = (tid == START_TAG) ? 1.f : 0.f;  // a_0 = onehot(start)
    } else {
      // g_init = exp(trans[end][i] - NEGV + em[S-1][i]); logoff_b = NEGV
      v = __expf(trans[END_TAG * Tn + tid] - NEGV +
                 embase[(size_t)(Sn - 1) * Tn + tid]);
    }
    sv[0][20 * (tid >> 4) + (tid & 15)] = v;
  }
  __syncthreads();

  // fwd: 511 matvecs -> a_511 ; bwd: 512 matvecs -> b_511 (meet at t=511)
  const int iters = isf ? (Sn / 2 - 1) : (Sn / 2);
  float logoff = isf ? 0.f : NEGV;
  f32x4 em4 = *(const f32x4*)(embase + (size_t)(isf ? 1 : (Sn - 2)) * Tn + 4 * g);
  f32x4 v4 = (f32x4){0.f, 0.f, 0.f, 0.f};

  for (int n = 1; n <= iters; ++n) {
    const bool mul = isf || (n < iters);  // bwd last matvec: no emission factor
    const bool has_next = isf ? (n < iters) : (n + 1 < iters);
    f32x4 em4n = em4;
    if (has_next) {
      const int idx = isf ? (n + 1) : (Sn - 2 - n);
      em4n = *(const f32x4*)(embase + (size_t)idx * Tn + 4 * g);  // prefetch
    }

    // deferred renorm apply: scale computed from max gathered last (n%4==3) step
    float scale = 1.f;
    if ((n & 3) == 0) {
      const f32x4 r4 = *(const f32x4*)red;
      const float m = fmaxf(fmaxf(r4.x, r4.y), fmaxf(r4.z, r4.w));
      scale = __builtin_amdgcn_rcpf(m);
      logoff += __logf(m);
    }

    const float* svr = sv[(n + 1) & 1] + 20 * s;
    const f32x4 S0 = *(const f32x4*)(svr);
    const f32x4 S1 = *(const f32x4*)(svr + 4);
    const f32x4 S2 = *(const f32x4*)(svr + 8);
    const f32x4 S3 = *(const f32x4*)(svr + 12);

    f32x4 acc = S0.x * E0;
    acc += S0.y * E1;
    acc += S0.z * E2;
    acc += S0.w * E3;
    acc += S1.x * E4;
    acc += S1.y * E5;
    acc += S1.z * E6;
    acc += S1.w * E7;
    acc += S2.x * E8;
    acc += S2.y * E9;
    acc += S2.z * E10;
    acc += S2.w * E11;
    acc += S3.x * E12;
    acc += S3.y * E13;
    acc += S3.z * E14;
    acc += S3.w * E15;

    // butterfly over the 8 depth-slices (lanes l^1, l^2, l^7) -> all lanes hold sum
    acc.x += dppf<0xB1>(acc.x);   // quad_perm(1,0,3,2) = xor1
    acc.y += dppf<0xB1>(acc.y);
    acc.z += dppf<0xB1>(acc.z);
    acc.w += dppf<0xB1>(acc.w);
    acc.x += dppf<0x4E>(acc.x);   // quad_perm(2,3,0,1) = xor2
    acc.y += dppf<0x4E>(acc.y);
    acc.z += dppf<0x4E>(acc.z);
    acc.w += dppf<0x4E>(acc.w);
    acc.x += dppf<0x141>(acc.x);  // row_half_mirror = xor7 (crosses quad pair)
    acc.y += dppf<0x141>(acc.y);
    acc.z += dppf<0x141>(acc.z);
    acc.w += dppf<0x141>(acc.w);

    f32x4 ex4;
    if (mul) {
      ex4 = (f32x4){__expf(em4.x), __expf(em4.y), __expf(em4.z), __expf(em4.w)};
    } else {
      ex4 = (f32x4){1.f, 1.f, 1.f, 1.f};
    }
    v4 = acc * ex4 * scale;

    if ((n & 3) == 3) {  // gather block max for next apply step
      float m = fmaxf(fmaxf(v4.x, v4.y), fmaxf(v4.z, v4.w));
      m = fmaxf(m, dppf<0x140>(m));  // row_mirror: merge 8-group pairs
      m = fmaxf(m, dppf<0x142>(m));  // row_bcast15
      m = fmaxf(m, dppf<0x143>(m));  // row_bcast31 -> lane63 has wave max
      m = rl63(m);
      if (l == 0) red[w] = m;
    }
    if (s == 0)
      *(f32x4*)(sv[n & 1] + 20 * (g >> 2) + 4 * (g & 3)) = v4;
    em4 = em4n;
    __syncthreads();
  }

  // final renormalize + store vector and log-offset
  {
    float m = fmaxf(fmaxf(v4.x, v4.y), fmaxf(v4.z, v4.w));
    m = fmaxf(m, dppf<0x140>(m));
    m = fmaxf(m, dppf<0x142>(m));
    m = fmaxf(m, dppf<0x143>(m));
    m = rl63(m);
    if (l == 0) red[w] = m;
  }
  __syncthreads();
  float* vec_out = ws + (isf ? 0 : Bn * Tn) + b * Tn;
  float* scal = ws + 2 * Bn * Tn + b * 4;
  {
    const f32x4 r4 = *(const f32x4*)red;
    const float mf = fmaxf(fmaxf(r4.x, r4.y), fmaxf(r4.z, r4.w));
    const float rs = __builtin_amdgcn_rcpf(mf);
    if (s == 0) {
      vec_out[4 * g + 0] = v4.x * rs;
      vec_out[4 * g + 1] = v4.y * rs;
      vec_out[4 * g + 2] = v4.z * rs;
      vec_out[4 * g + 3] = v4.w * rs;
    }
    if (tid == 0) scal[isf ? 0 : 2] = logoff + __logf(mf);
  }

  // ---- gold path score (each chain covers its half of t) ----
  const int* tg = tags + b * Sn;
  float gsum = 0.f;
  const int t0 = isf ? 0 : (Sn / 2);
  for (int t = t0 + tid; t < t0 + Sn / 2; t += 256) {
    const int tag = tg[t];
    gsum += embase[(size_t)t * Tn + tag];
    if (isf) {
      if (t < Sn / 2 - 1) gsum += trans[tag * Tn + tg[t + 1]];
    } else {
      gsum += trans[tg[t - 1] * Tn + tag];  // covers pairs (511,512)..(1022,1023)
    }
  }
  if (tid == 0)
    gsum += isf ? trans[START_TAG * Tn + tg[0]] : trans[tg[Sn - 1] * Tn + END_TAG];
  gsum = wave_sum(gsum);
  if (l == 0) gred[w] = gsum;
  __syncthreads();
  if (tid == 0) scal[isf ? 1 : 3] = gred[0] + gred[1] + gred[2] + gred[3];
}

__global__ void crf_final(const float* __restrict__ ws, float* __restrict__ out) {
  const int tid = threadIdx.x;  // 256 threads = one per batch
  const float* av = ws + tid * Tn;
  const float* bv = ws + Bn * Tn + tid * Tn;
  const float* scal = ws + 2 * Bn * Tn + tid * 4;
  float dot = 0.f;
#pragma unroll 4
  for (int k = 0; k < Tn / 4; ++k) {
    const float4 a4 = reinterpret_cast<const float4*>(av)[k];
    const float4 b4 = reinterpret_cast<const float4*>(bv)[k];
    dot += a4.x * b4.x + a4.y * b4.y + a4.z * b4.z + a4.w * b4.w;
  }
  const float partition = scal[0] + scal[2] + __logf(dot);
  const float loss = partition - scal[1] - scal[3];
  float ssum = wave_sum(loss);
  __shared__ float r[4];
  if ((tid & 63) == 0) r[tid >> 6] = ssum;
  __syncthreads();
  if (tid == 0) out[0] = (r[0] + r[1] + r[2] + r[3]) * (1.f / Bn);
}

}  // namespace

extern "C" void kernel_launch(void* const* d_in, const int* in_sizes, int n_in,
                              void* d_out, int out_size, void* d_ws, size_t ws_size,
                              hipStream_t stream) {
  (void)in_sizes; (void)n_in; (void)out_size; (void)ws_size;
  const float* em = (const float*)d_in[0];
  const int* tags = (const int*)d_in[1];
  const float* trans = (const float*)d_in[2];
  float* out = (float*)d_out;
  float* ws = (float*)d_ws;

  crf_chain<<<dim3(2 * Bn), dim3(256), 0, stream>>>(em, tags, trans, ws);
  crf_final<<<dim3(1), dim3(256), 0, stream>>>(ws, out);
}